// Round 1
// baseline (3574.240 us; speedup 1.0000x reference)
//
#include <hip/hip_runtime.h>
#include <hip/hip_bf16.h>
#include <cstdint>
#include <cstddef>

typedef _Float16 f16;
typedef _Float16 f16x8 __attribute__((ext_vector_type(8)));
typedef float f32x4 __attribute__((ext_vector_type(4)));

#define DIMK 4096
#define HIDK 11008
#define MTOK 8192

// ---- async global->LDS, 16B per lane, dest = ldsbase + lane*16 ----
__device__ __forceinline__ void gld_lds16(const void* g, void* l) {
  __builtin_amdgcn_global_load_lds(
      (const __attribute__((address_space(1))) void*)g,
      (__attribute__((address_space(3))) void*)l, 16, 0, 0);
}

// ---- fp32 -> fp16 convert, 8 elems/thread, grid-stride ----
__global__ __launch_bounds__(256) void convertk(const float* __restrict__ s,
                                                f16* __restrict__ d, int n) {
  for (int i = ((int)blockIdx.x * 256 + (int)threadIdx.x) * 8; i < n;
       i += (int)gridDim.x * 256 * 8) {
    const float4* p = (const float4*)(s + i);
    float4 a = p[0], b = p[1];
    f16x8 o;
    o[0] = (f16)a.x; o[1] = (f16)a.y; o[2] = (f16)a.z; o[3] = (f16)a.w;
    o[4] = (f16)b.x; o[5] = (f16)b.y; o[6] = (f16)b.z; o[7] = (f16)b.w;
    *(f16x8*)(d + i) = o;
  }
}

// ---- t1 = x@A1^T, t3 = x@A3^T  (K=4096, one wave per row) ----
__global__ __launch_bounds__(256) void lora_xA(const f16* __restrict__ xh,
                                               const float* __restrict__ A1,
                                               const float* __restrict__ A3,
                                               float* __restrict__ t1,
                                               float* __restrict__ t3) {
  const int wid = threadIdx.x >> 6, l = threadIdx.x & 63;
  const int m = (int)blockIdx.x * 4 + wid;
  float a1[16], a3[16];
#pragma unroll
  for (int r = 0; r < 16; ++r) { a1[r] = 0.f; a3[r] = 0.f; }
  for (int it = 0; it < 8; ++it) {
    const int k0 = it * 512 + l * 8;
    f16x8 xv = *(const f16x8*)(xh + (size_t)m * DIMK + k0);
    float xf[8];
#pragma unroll
    for (int j = 0; j < 8; ++j) xf[j] = (float)xv[j];
#pragma unroll
    for (int r = 0; r < 16; ++r) {
      const float4* p1 = (const float4*)(A1 + (size_t)r * DIMK + k0);
      float4 u = p1[0], v = p1[1];
      a1[r] += xf[0]*u.x + xf[1]*u.y + xf[2]*u.z + xf[3]*u.w +
               xf[4]*v.x + xf[5]*v.y + xf[6]*v.z + xf[7]*v.w;
      const float4* p3 = (const float4*)(A3 + (size_t)r * DIMK + k0);
      float4 s2 = p3[0], t2v = p3[1];
      a3[r] += xf[0]*s2.x + xf[1]*s2.y + xf[2]*s2.z + xf[3]*s2.w +
               xf[4]*t2v.x + xf[5]*t2v.y + xf[6]*t2v.z + xf[7]*t2v.w;
    }
  }
#pragma unroll
  for (int r = 0; r < 16; ++r) {
    float v1 = a1[r], v3 = a3[r];
#pragma unroll
    for (int off = 32; off > 0; off >>= 1) {
      v1 += __shfl_xor(v1, off);
      v3 += __shfl_xor(v3, off);
    }
    if (l == 0) { t1[m * 16 + r] = v1; t3[m * 16 + r] = v3; }
  }
}

// ---- t2 = g@A2^T (K=11008) ----
__global__ __launch_bounds__(256) void lora_g(const f16* __restrict__ gh,
                                              const float* __restrict__ A2,
                                              float* __restrict__ t2) {
  const int wid = threadIdx.x >> 6, l = threadIdx.x & 63;
  const int m = (int)blockIdx.x * 4 + wid;
  float acc[16];
#pragma unroll
  for (int r = 0; r < 16; ++r) acc[r] = 0.f;
  for (int it = 0; it < 22; ++it) {
    const int k0 = it * 512 + l * 8;
    if (k0 < HIDK) {
      f16x8 gv = *(const f16x8*)(gh + (size_t)m * HIDK + k0);
      float xf[8];
#pragma unroll
      for (int j = 0; j < 8; ++j) xf[j] = (float)gv[j];
#pragma unroll
      for (int r = 0; r < 16; ++r) {
        const float4* p = (const float4*)(A2 + (size_t)r * HIDK + k0);
        float4 u = p[0], v = p[1];
        acc[r] += xf[0]*u.x + xf[1]*u.y + xf[2]*u.z + xf[3]*u.w +
                  xf[4]*v.x + xf[5]*v.y + xf[6]*v.z + xf[7]*v.w;
      }
    }
  }
#pragma unroll
  for (int r = 0; r < 16; ++r) {
    float v = acc[r];
#pragma unroll
    for (int off = 32; off > 0; off >>= 1) v += __shfl_xor(v, off);
    if (l == 0) t2[m * 16 + r] = v;
  }
}

// ---- fused gate GEMM: g = silu(x@w1^T + 2 t1@B1^T) * (x@w3^T + 2 t3@B3^T) ----
// 128x128 tile, BK=64, 4 waves, dual accumulators, LoRA folded as extra K-step.
__global__ __launch_bounds__(256, 2) void gemm_gate(
    const f16* __restrict__ xh, const f16* __restrict__ w1h,
    const f16* __restrict__ w3h, const float* __restrict__ t1,
    const float* __restrict__ t3, const float* __restrict__ B1,
    const float* __restrict__ B3, f16* __restrict__ gh) {
  __shared__ __align__(16) char sX[16384];
  __shared__ __align__(16) char sW1[16384];
  __shared__ __align__(16) char sW3[16384];

  const int bid = (int)blockIdx.x;
  const int wg = (bid & 7) * 688 + (bid >> 3);  // XCD swizzle, 5504 % 8 == 0
  const int tm = wg & 63, tn = wg >> 6;         // m-fastest: share w-panel in L2
  const int M0 = tm * 128, N0 = tn * 128;

  const int tid = threadIdx.x;
  const int wid = tid >> 6, l = tid & 63;
  const int wr = wid >> 1, wc = wid & 1;

  const f32x4 zz = {0.f, 0.f, 0.f, 0.f};
  f32x4 acc1[4][4], acc3[4][4];
#pragma unroll
  for (int i = 0; i < 4; ++i)
#pragma unroll
    for (int j = 0; j < 4; ++j) { acc1[i][j] = zz; acc3[i][j] = zz; }

  // staging: lane -> 16B; LDS linear, global source pre-swizzled (xor (row&7)<<4)
  const int rl = l >> 3, cb = (l & 7) << 4;
  const int scb = cb ^ (rl << 4);
  const char* xg = (const char*)xh + ((size_t)(M0 + wid * 32 + rl) << 13) + scb;
  const char* w1g = (const char*)w1h + ((size_t)(N0 + wid * 32 + rl) << 13) + scb;
  const char* w3g = (const char*)w3h + ((size_t)(N0 + wid * 32 + rl) << 13) + scb;
  char* lX = sX + wid * 4096;
  char* lW1 = sW1 + wid * 4096;
  char* lW3 = sW3 + wid * 4096;

  for (int kb = 0; kb < 64; ++kb) {
    const size_t ko = (size_t)kb << 7;
#pragma unroll
    for (int q = 0; q < 4; ++q) {
      gld_lds16(xg + ko + q * 65536, lX + q * 1024);
      gld_lds16(w1g + ko + q * 65536, lW1 + q * 1024);
      gld_lds16(w3g + ko + q * 65536, lW3 + q * 1024);
    }
    asm volatile("s_waitcnt vmcnt(0)" ::: "memory");
    __syncthreads();
#pragma unroll
    for (int ks = 0; ks < 2; ++ks) {
      const int clin = ks * 64 + ((l >> 4) << 4);
      const int sx = (l & 7) << 4;
      f16x8 a[4];
#pragma unroll
      for (int i = 0; i < 4; ++i)
        a[i] = *(const f16x8*)(sX + ((wr * 64 + i * 16 + (l & 15)) << 7) +
                               (clin ^ sx));
#pragma unroll
      for (int j = 0; j < 4; ++j) {
        const int off =
            ((wc * 64 + j * 16 + (l & 15)) << 7) + (clin ^ sx);
        const f16x8 b1 = *(const f16x8*)(sW1 + off);
        const f16x8 b3 = *(const f16x8*)(sW3 + off);
#pragma unroll
        for (int i = 0; i < 4; ++i) {
          acc1[i][j] = __builtin_amdgcn_mfma_f32_16x16x32_f16(a[i], b1, acc1[i][j], 0, 0, 0);
          acc3[i][j] = __builtin_amdgcn_mfma_f32_16x16x32_f16(a[i], b3, acc3[i][j], 0, 0, 0);
        }
      }
    }
    __syncthreads();
  }

  // ---- LoRA ext K-step: A=[2t1|2t3], B1ext=[B1|0], B3ext=[0|B3] ----
  {
    const int row = tid >> 1, h = tid & 1;
    const int s = (row & 7) << 4;
    const int c0 = h << 5;
    const float* sa = h ? (t3 + (size_t)(M0 + row) * 16)
                        : (t1 + (size_t)(M0 + row) * 16);
    f16x8 lo, hi;
#pragma unroll
    for (int r = 0; r < 8; ++r) {
      lo[r] = (f16)(2.0f * sa[r]);
      hi[r] = (f16)(2.0f * sa[r + 8]);
    }
    char* prX = sX + (row << 7);
    *(f16x8*)(prX + (c0 ^ s)) = lo;
    *(f16x8*)(prX + ((c0 + 16) ^ s)) = hi;

    const float* sb1 = B1 + (size_t)(N0 + row) * 16;
    const float* sb3 = B3 + (size_t)(N0 + row) * 16;
    f16x8 v1lo, v1hi, v3lo, v3hi;
#pragma unroll
    for (int r = 0; r < 8; ++r) {
      if (h == 0) {
        v1lo[r] = (f16)sb1[r]; v1hi[r] = (f16)sb1[r + 8];
        v3lo[r] = (f16)0.f;    v3hi[r] = (f16)0.f;
      } else {
        v1lo[r] = (f16)0.f;    v1hi[r] = (f16)0.f;
        v3lo[r] = (f16)sb3[r]; v3hi[r] = (f16)sb3[r + 8];
      }
    }
    char* pr1 = sW1 + (row << 7);
    char* pr3 = sW3 + (row << 7);
    *(f16x8*)(pr1 + (c0 ^ s)) = v1lo;
    *(f16x8*)(pr1 + ((c0 + 16) ^ s)) = v1hi;
    *(f16x8*)(pr3 + (c0 ^ s)) = v3lo;
    *(f16x8*)(pr3 + ((c0 + 16) ^ s)) = v3hi;
  }
  __syncthreads();
  {
    const int clin = (l >> 4) << 4;
    const int sx = (l & 7) << 4;
    f16x8 a[4];
#pragma unroll
    for (int i = 0; i < 4; ++i)
      a[i] = *(const f16x8*)(sX + ((wr * 64 + i * 16 + (l & 15)) << 7) +
                             (clin ^ sx));
#pragma unroll
    for (int j = 0; j < 4; ++j) {
      const int off = ((wc * 64 + j * 16 + (l & 15)) << 7) + (clin ^ sx);
      const f16x8 b1 = *(const f16x8*)(sW1 + off);
      const f16x8 b3 = *(const f16x8*)(sW3 + off);
#pragma unroll
      for (int i = 0; i < 4; ++i) {
        acc1[i][j] = __builtin_amdgcn_mfma_f32_16x16x32_f16(a[i], b1, acc1[i][j], 0, 0, 0);
        acc3[i][j] = __builtin_amdgcn_mfma_f32_16x16x32_f16(a[i], b3, acc3[i][j], 0, 0, 0);
      }
    }
  }

  // ---- epilogue: g = silu(h1) * h3, store fp16 ----
#pragma unroll
  for (int i = 0; i < 4; ++i)
#pragma unroll
    for (int j = 0; j < 4; ++j) {
      const int n = N0 + wc * 64 + j * 16 + (l & 15);
#pragma unroll
      for (int r = 0; r < 4; ++r) {
        const int m = M0 + wr * 64 + i * 16 + ((l >> 4) << 2) + r;
        const float h1 = acc1[i][j][r], h3 = acc3[i][j][r];
        const float gg = h1 * h3 / (1.f + __expf(-h1));
        gh[(size_t)m * HIDK + n] = (f16)gg;
      }
    }
}

// ---- output GEMM: out = g@w2^T + 2 t2@B2^T  (K=11008, LoRA ext step) ----
__global__ __launch_bounds__(256, 2) void gemm_out(
    const f16* __restrict__ gh, const f16* __restrict__ w2h,
    const float* __restrict__ t2, const float* __restrict__ B2,
    float* __restrict__ out) {
  __shared__ __align__(16) char sG[16384];
  __shared__ __align__(16) char sW[16384];

  const int bid = (int)blockIdx.x;
  const int wg = (bid & 7) * 256 + (bid >> 3);  // 2048 % 8 == 0
  const int tm = wg & 63, tn = wg >> 6;
  const int M0 = tm * 128, N0 = tn * 128;

  const int tid = threadIdx.x;
  const int wid = tid >> 6, l = tid & 63;
  const int wr = wid >> 1, wc = wid & 1;

  const f32x4 zz = {0.f, 0.f, 0.f, 0.f};
  f32x4 acc[4][4];
#pragma unroll
  for (int i = 0; i < 4; ++i)
#pragma unroll
    for (int j = 0; j < 4; ++j) acc[i][j] = zz;

  const int rl = l >> 3, cb = (l & 7) << 4;
  const int scb = cb ^ (rl << 4);
  const size_t RS = (size_t)HIDK * 2;  // 22016 B row stride
  const char* gg = (const char*)gh + (size_t)(M0 + wid * 32 + rl) * RS + scb;
  const char* wg2 = (const char*)w2h + (size_t)(N0 + wid * 32 + rl) * RS + scb;
  char* lG = sG + wid * 4096;
  char* lW = sW + wid * 4096;

  for (int kb = 0; kb < 172; ++kb) {
    const size_t ko = (size_t)kb << 7;
#pragma unroll
    for (int q = 0; q < 4; ++q) {
      gld_lds16(gg + ko + q * 8 * RS, lG + q * 1024);
      gld_lds16(wg2 + ko + q * 8 * RS, lW + q * 1024);
    }
    asm volatile("s_waitcnt vmcnt(0)" ::: "memory");
    __syncthreads();
#pragma unroll
    for (int ks = 0; ks < 2; ++ks) {
      const int clin = ks * 64 + ((l >> 4) << 4);
      const int sx = (l & 7) << 4;
      f16x8 a[4];
#pragma unroll
      for (int i = 0; i < 4; ++i)
        a[i] = *(const f16x8*)(sG + ((wr * 64 + i * 16 + (l & 15)) << 7) +
                               (clin ^ sx));
#pragma unroll
      for (int j = 0; j < 4; ++j) {
        const int off = ((wc * 64 + j * 16 + (l & 15)) << 7) + (clin ^ sx);
        const f16x8 b = *(const f16x8*)(sW + off);
#pragma unroll
        for (int i = 0; i < 4; ++i)
          acc[i][j] = __builtin_amdgcn_mfma_f32_16x16x32_f16(a[i], b, acc[i][j], 0, 0, 0);
      }
    }
    __syncthreads();
  }

  // LoRA ext: A=[2 t2 | 0], B=[B2 | 0]
  {
    const int row = tid >> 1, h = tid & 1;
    const int s = (row & 7) << 4;
    const int c0 = h << 5;
    f16x8 alo, ahi, blo, bhi;
    if (h == 0) {
      const float* sa = t2 + (size_t)(M0 + row) * 16;
      const float* sb = B2 + (size_t)(N0 + row) * 16;
#pragma unroll
      for (int r = 0; r < 8; ++r) {
        alo[r] = (f16)(2.0f * sa[r]); ahi[r] = (f16)(2.0f * sa[r + 8]);
        blo[r] = (f16)sb[r];          bhi[r] = (f16)sb[r + 8];
      }
    } else {
#pragma unroll
      for (int r = 0; r < 8; ++r) {
        alo[r] = (f16)0.f; ahi[r] = (f16)0.f;
        blo[r] = (f16)0.f; bhi[r] = (f16)0.f;
      }
    }
    char* prG = sG + (row << 7);
    char* prW = sW + (row << 7);
    *(f16x8*)(prG + (c0 ^ s)) = alo;
    *(f16x8*)(prG + ((c0 + 16) ^ s)) = ahi;
    *(f16x8*)(prW + (c0 ^ s)) = blo;
    *(f16x8*)(prW + ((c0 + 16) ^ s)) = bhi;
  }
  __syncthreads();
  {
    const int clin = (l >> 4) << 4;
    const int sx = (l & 7) << 4;
    f16x8 a[4];
#pragma unroll
    for (int i = 0; i < 4; ++i)
      a[i] = *(const f16x8*)(sG + ((wr * 64 + i * 16 + (l & 15)) << 7) +
                             (clin ^ sx));
#pragma unroll
    for (int j = 0; j < 4; ++j) {
      const int off = ((wc * 64 + j * 16 + (l & 15)) << 7) + (clin ^ sx);
      const f16x8 b = *(const f16x8*)(sW + off);
#pragma unroll
      for (int i = 0; i < 4; ++i)
        acc[i][j] = __builtin_amdgcn_mfma_f32_16x16x32_f16(a[i], b, acc[i][j], 0, 0, 0);
    }
  }

#pragma unroll
  for (int i = 0; i < 4; ++i)
#pragma unroll
    for (int j = 0; j < 4; ++j) {
      const int n = N0 + wc * 64 + j * 16 + (l & 15);
#pragma unroll
      for (int r = 0; r < 4; ++r) {
        const int m = M0 + wr * 64 + i * 16 + ((l >> 4) << 2) + r;
        out[(size_t)m * DIMK + n] = acc[i][j][r];
      }
    }
}

extern "C" void kernel_launch(void* const* d_in, const int* in_sizes, int n_in,
                              void* d_out, int out_size, void* d_ws,
                              size_t ws_size, hipStream_t stream) {
  (void)in_sizes; (void)n_in; (void)out_size; (void)ws_size;
  const float* x = (const float*)d_in[0];
  const float* w1 = (const float*)d_in[1];
  const float* w3 = (const float*)d_in[2];
  const float* w2 = (const float*)d_in[3];
  const float* A1 = (const float*)d_in[4];
  const float* B1 = (const float*)d_in[5];
  const float* A3 = (const float*)d_in[6];
  const float* B3 = (const float*)d_in[7];
  const float* A2 = (const float*)d_in[8];
  const float* B2 = (const float*)d_in[9];
  float* out = (float*)d_out;
  char* ws = (char*)d_ws;

  // workspace layout (total ~495.5 MiB)
  f16* xh = (f16*)(ws);                                   //  64 MiB
  f16* w1h = (f16*)(ws + 67108864);                       //  86 MiB
  f16* w3h = (f16*)(ws + 67108864 + 90177536);            //  86 MiB
  f16* w2h = (f16*)(ws + 67108864 + 2 * 90177536);        //  86 MiB
  f16* gh = (f16*)(ws + 67108864 + 3 * 90177536);         // 172 MiB
  float* t1 = (float*)(ws + 67108864 + 3 * 90177536 + 180355072);
  float* t3 = t1 + MTOK * 16;
  float* t2 = t3 + MTOK * 16;

  convertk<<<1024, 256, 0, stream>>>(x, xh, MTOK * DIMK);
  convertk<<<1024, 256, 0, stream>>>(w1, w1h, HIDK * DIMK);
  convertk<<<1024, 256, 0, stream>>>(w3, w3h, HIDK * DIMK);
  convertk<<<1024, 256, 0, stream>>>(w2, w2h, DIMK * HIDK);
  lora_xA<<<MTOK / 4, 256, 0, stream>>>(xh, A1, A3, t1, t3);
  gemm_gate<<<(MTOK / 128) * (HIDK / 128), 256, 0, stream>>>(xh, w1h, w3h, t1,
                                                             t3, B1, B3, gh);
  lora_g<<<MTOK / 4, 256, 0, stream>>>(gh, A2, t2);
  gemm_out<<<(MTOK / 128) * (DIMK / 128), 256, 0, stream>>>(gh, w2h, t2, B2,
                                                            out);
}

// Round 3
// 3444.952 us; speedup vs baseline: 1.0375x; 1.0375x over previous
//
#include <hip/hip_runtime.h>
#include <hip/hip_bf16.h>
#include <cstdint>
#include <cstddef>

typedef _Float16 f16;
typedef _Float16 f16x8 __attribute__((ext_vector_type(8)));
typedef float f32x4 __attribute__((ext_vector_type(4)));

#define DIMK 4096
#define HIDK 11008
#define MTOK 8192

// ---- async global->LDS, 16B per lane, dest = wave-uniform base + lane*16 ----
__device__ __forceinline__ void gld_lds16(const void* g, void* l) {
  __builtin_amdgcn_global_load_lds(
      (const __attribute__((address_space(1))) void*)g,
      (__attribute__((address_space(3))) void*)l, 16, 0, 0);
}

// ---- fp32 -> fp16 convert, 8 elems/thread, grid-stride ----
__global__ __launch_bounds__(256) void convertk(const float* __restrict__ s,
                                                f16* __restrict__ d, int n) {
  for (int i = ((int)blockIdx.x * 256 + (int)threadIdx.x) * 8; i < n;
       i += (int)gridDim.x * 256 * 8) {
    const float4* p = (const float4*)(s + i);
    float4 a = p[0], b = p[1];
    f16x8 o;
    o[0] = (f16)a.x; o[1] = (f16)a.y; o[2] = (f16)a.z; o[3] = (f16)a.w;
    o[4] = (f16)b.x; o[5] = (f16)b.y; o[6] = (f16)b.z; o[7] = (f16)b.w;
    *(f16x8*)(d + i) = o;
  }
}

// ---- t1 = x@A1^T, t3 = x@A3^T  (K=4096, one wave per row) ----
__global__ __launch_bounds__(256) void lora_xA(const f16* __restrict__ xh,
                                               const float* __restrict__ A1,
                                               const float* __restrict__ A3,
                                               float* __restrict__ t1,
                                               float* __restrict__ t3) {
  const int wid = threadIdx.x >> 6, l = threadIdx.x & 63;
  const int m = (int)blockIdx.x * 4 + wid;
  float a1[16], a3[16];
#pragma unroll
  for (int r = 0; r < 16; ++r) { a1[r] = 0.f; a3[r] = 0.f; }
  for (int it = 0; it < 8; ++it) {
    const int k0 = it * 512 + l * 8;
    f16x8 xv = *(const f16x8*)(xh + (size_t)m * DIMK + k0);
    float xf[8];
#pragma unroll
    for (int j = 0; j < 8; ++j) xf[j] = (float)xv[j];
#pragma unroll
    for (int r = 0; r < 16; ++r) {
      const float4* p1 = (const float4*)(A1 + (size_t)r * DIMK + k0);
      float4 u = p1[0], v = p1[1];
      a1[r] += xf[0]*u.x + xf[1]*u.y + xf[2]*u.z + xf[3]*u.w +
               xf[4]*v.x + xf[5]*v.y + xf[6]*v.z + xf[7]*v.w;
      const float4* p3 = (const float4*)(A3 + (size_t)r * DIMK + k0);
      float4 s2 = p3[0], t2v = p3[1];
      a3[r] += xf[0]*s2.x + xf[1]*s2.y + xf[2]*s2.z + xf[3]*s2.w +
               xf[4]*t2v.x + xf[5]*t2v.y + xf[6]*t2v.z + xf[7]*t2v.w;
    }
  }
#pragma unroll
  for (int r = 0; r < 16; ++r) {
    float v1 = a1[r], v3 = a3[r];
#pragma unroll
    for (int off = 32; off > 0; off >>= 1) {
      v1 += __shfl_xor(v1, off);
      v3 += __shfl_xor(v3, off);
    }
    if (l == 0) { t1[m * 16 + r] = v1; t3[m * 16 + r] = v3; }
  }
}

// ---- t2 = g@A2^T (K=11008) ----
__global__ __launch_bounds__(256) void lora_g(const f16* __restrict__ gh,
                                              const float* __restrict__ A2,
                                              float* __restrict__ t2) {
  const int wid = threadIdx.x >> 6, l = threadIdx.x & 63;
  const int m = (int)blockIdx.x * 4 + wid;
  float acc[16];
#pragma unroll
  for (int r = 0; r < 16; ++r) acc[r] = 0.f;
  for (int it = 0; it < 22; ++it) {
    const int k0 = it * 512 + l * 8;
    if (k0 < HIDK) {
      f16x8 gv = *(const f16x8*)(gh + (size_t)m * HIDK + k0);
      float xf[8];
#pragma unroll
      for (int j = 0; j < 8; ++j) xf[j] = (float)gv[j];
#pragma unroll
      for (int r = 0; r < 16; ++r) {
        const float4* p = (const float4*)(A2 + (size_t)r * HIDK + k0);
        float4 u = p[0], v = p[1];
        acc[r] += xf[0]*u.x + xf[1]*u.y + xf[2]*u.z + xf[3]*u.w +
                  xf[4]*v.x + xf[5]*v.y + xf[6]*v.z + xf[7]*v.w;
      }
    }
  }
#pragma unroll
  for (int r = 0; r < 16; ++r) {
    float v = acc[r];
#pragma unroll
    for (int off = 32; off > 0; off >>= 1) v += __shfl_xor(v, off);
    if (l == 0) t2[m * 16 + r] = v;
  }
}

// ============================================================================
// Pipelined dual GEMM: g = silu(x@w1^T + 2 t1@B1^T) * (x@w3^T + 2 t3@B3^T)
// BM=256, BN=128 (x2 outputs), BK=32, 4 LDS buffers, counted vmcnt(8),
// raw s_barrier (never drains vmcnt), setprio around MFMA clusters.
// ============================================================================
#define GNT 128  // 4096 / 32
__global__ __launch_bounds__(512, 2) void gemm_gate(
    const f16* __restrict__ xh, const f16* __restrict__ w1h,
    const f16* __restrict__ w3h, const float* __restrict__ t1,
    const float* __restrict__ t3, const float* __restrict__ B1,
    const float* __restrict__ B3, f16* __restrict__ gh) {
  __shared__ __align__(16) char lds[131072];  // 4 bufs x (A 16K | B1 8K | B3 8K)

  const int bid = (int)blockIdx.x;
  const int wg = (bid & 7) * 344 + (bid >> 3);  // XCD swizzle, 2752 % 8 == 0
  const int tm = wg & 31, tn = wg >> 5;         // m-fastest: w-panel L2 reuse
  const int M0 = tm << 8, N0 = tn << 7;

  const int tid = (int)threadIdx.x;
  const int l = tid & 63, wid = tid >> 6;
  const int wr = wid >> 2, wc = wid & 3;  // 2 x 4 waves -> 128 x 32 per wave
  const int rA = l & 15;

  // staging sources (pre-swizzled global col so linear LDS dest == swizzled)
  const int srow = l >> 2;
  const int scol = ((l & 3) ^ ((l >> 3) & 3)) << 4;
  const uint8_t* aSrc =
      (const uint8_t*)xh + (size_t)(M0 + wid * 32 + srow) * 8192 + scol;
  const uint8_t* b1Src =
      (const uint8_t*)w1h + (size_t)(N0 + wid * 16 + srow) * 8192 + scol;
  const uint8_t* b3Src =
      (const uint8_t*)w3h + (size_t)(N0 + wid * 16 + srow) * 8192 + scol;

  // fragment read offsets (swizzled)
  const int colA = ((l >> 4) ^ ((l >> 1) & 3)) << 4;
  const int aOff = ((wr * 128 + rA) << 6) + colA;  // + i*1024
  const int bOff = ((wc * 32 + rA) << 6) + colA;   // + j*1024

  const f32x4 zz = {0.f, 0.f, 0.f, 0.f};
  f32x4 acc1[8][2], acc3[8][2];
#pragma unroll
  for (int i = 0; i < 8; ++i)
#pragma unroll
    for (int j = 0; j < 2; ++j) { acc1[i][j] = zz; acc3[i][j] = zz; }

  // prologue: stage tiles 0..2
#pragma unroll
  for (int pt = 0; pt < 3; ++pt) {
    const int bb = pt << 15;
    const size_t o = (size_t)pt * 64;
    gld_lds16(aSrc + o, lds + bb + wid * 2048);
    gld_lds16(aSrc + o + 131072, lds + bb + wid * 2048 + 1024);
    gld_lds16(b1Src + o, lds + bb + 16384 + wid * 1024);
    gld_lds16(b3Src + o, lds + bb + 24576 + wid * 1024);
  }
  asm volatile("s_waitcnt vmcnt(8)" ::: "memory");
  __builtin_amdgcn_s_barrier();

  for (int t = 0; t < GNT; ++t) {
    const int bb = (t & 3) << 15;
    f16x8 a[8], b1[2], b3[2];
    // ---- phase A: frags + A-prefetch, MFMA i0-3 ----
#pragma unroll
    for (int i = 0; i < 4; ++i)
      a[i] = *(const f16x8*)(lds + bb + aOff + i * 1024);
#pragma unroll
    for (int j = 0; j < 2; ++j) {
      b1[j] = *(const f16x8*)(lds + bb + 16384 + bOff + j * 1024);
      b3[j] = *(const f16x8*)(lds + bb + 24576 + bOff + j * 1024);
    }
    if (t + 3 < GNT) {
      const int nb = ((t + 3) & 3) << 15;
      const size_t o = (size_t)(t + 3) * 64;
      gld_lds16(aSrc + o, lds + nb + wid * 2048);
      gld_lds16(aSrc + o + 131072, lds + nb + wid * 2048 + 1024);
    }
    __builtin_amdgcn_s_barrier();
    asm volatile("s_waitcnt lgkmcnt(0)" ::: "memory");
    __builtin_amdgcn_sched_barrier(0);
    __builtin_amdgcn_s_setprio(1);
#pragma unroll
    for (int i = 0; i < 4; ++i)
#pragma unroll
      for (int j = 0; j < 2; ++j) {
        acc1[i][j] = __builtin_amdgcn_mfma_f32_16x16x32_f16(a[i], b1[j], acc1[i][j], 0, 0, 0);
        acc3[i][j] = __builtin_amdgcn_mfma_f32_16x16x32_f16(a[i], b3[j], acc3[i][j], 0, 0, 0);
      }
    __builtin_amdgcn_s_setprio(0);
    __builtin_amdgcn_s_barrier();
    // ---- phase B: frags + B-prefetch, counted vmcnt, MFMA i4-7 ----
#pragma unroll
    for (int i = 4; i < 8; ++i)
      a[i] = *(const f16x8*)(lds + bb + aOff + i * 1024);
    if (t + 3 < GNT) {
      const int nb = ((t + 3) & 3) << 15;
      const size_t o = (size_t)(t + 3) * 64;
      gld_lds16(b1Src + o, lds + nb + 16384 + wid * 1024);
      gld_lds16(b3Src + o, lds + nb + 24576 + wid * 1024);
    }
    if (t + 3 < GNT)      asm volatile("s_waitcnt vmcnt(8)" ::: "memory");
    else if (t + 3 == GNT) asm volatile("s_waitcnt vmcnt(4)" ::: "memory");
    else if (t + 2 == GNT) asm volatile("s_waitcnt vmcnt(0)" ::: "memory");
    __builtin_amdgcn_s_barrier();
    asm volatile("s_waitcnt lgkmcnt(0)" ::: "memory");
    __builtin_amdgcn_sched_barrier(0);
    __builtin_amdgcn_s_setprio(1);
#pragma unroll
    for (int i = 4; i < 8; ++i)
#pragma unroll
      for (int j = 0; j < 2; ++j) {
        acc1[i][j] = __builtin_amdgcn_mfma_f32_16x16x32_f16(a[i], b1[j], acc1[i][j], 0, 0, 0);
        acc3[i][j] = __builtin_amdgcn_mfma_f32_16x16x32_f16(a[i], b3[j], acc3[i][j], 0, 0, 0);
      }
    __builtin_amdgcn_s_setprio(0);
    __builtin_amdgcn_s_barrier();
  }

  // ---- LoRA ext K=32 step, register-direct: A=[2t1|2t3], B1e=[B1|0], B3e=[0|B3]
  const int kg = l >> 4;
  {
    f16x8 bx1[2], bx3[2];
#pragma unroll
    for (int j = 0; j < 2; ++j) {
      const int n = N0 + wc * 32 + j * 16 + rA;
#pragma unroll
      for (int e = 0; e < 8; ++e) { bx1[j][e] = (f16)0.f; bx3[j][e] = (f16)0.f; }
      if (kg < 2) {
        const float4* p = (const float4*)(B1 + (size_t)n * 16 + kg * 8);
        float4 u = p[0], v = p[1];
        bx1[j][0]=(f16)u.x; bx1[j][1]=(f16)u.y; bx1[j][2]=(f16)u.z; bx1[j][3]=(f16)u.w;
        bx1[j][4]=(f16)v.x; bx1[j][5]=(f16)v.y; bx1[j][6]=(f16)v.z; bx1[j][7]=(f16)v.w;
      } else {
        const float4* p = (const float4*)(B3 + (size_t)n * 16 + (kg - 2) * 8);
        float4 u = p[0], v = p[1];
        bx3[j][0]=(f16)u.x; bx3[j][1]=(f16)u.y; bx3[j][2]=(f16)u.z; bx3[j][3]=(f16)u.w;
        bx3[j][4]=(f16)v.x; bx3[j][5]=(f16)v.y; bx3[j][6]=(f16)v.z; bx3[j][7]=(f16)v.w;
      }
    }
#pragma unroll
    for (int i = 0; i < 8; ++i) {
      const int m = M0 + wr * 128 + i * 16 + rA;
      const float* src = (kg < 2) ? (t1 + (size_t)m * 16 + kg * 8)
                                  : (t3 + (size_t)m * 16 + (kg - 2) * 8);
      const float4* p = (const float4*)src;
      float4 u = p[0], v = p[1];
      f16x8 ax;
      ax[0]=(f16)(2.f*u.x); ax[1]=(f16)(2.f*u.y); ax[2]=(f16)(2.f*u.z); ax[3]=(f16)(2.f*u.w);
      ax[4]=(f16)(2.f*v.x); ax[5]=(f16)(2.f*v.y); ax[6]=(f16)(2.f*v.z); ax[7]=(f16)(2.f*v.w);
#pragma unroll
      for (int j = 0; j < 2; ++j) {
        acc1[i][j] = __builtin_amdgcn_mfma_f32_16x16x32_f16(ax, bx1[j], acc1[i][j], 0, 0, 0);
        acc3[i][j] = __builtin_amdgcn_mfma_f32_16x16x32_f16(ax, bx3[j], acc3[i][j], 0, 0, 0);
      }
    }
  }

  // ---- epilogue: g = silu(h1) * h3 ----
#pragma unroll
  for (int i = 0; i < 8; ++i)
#pragma unroll
    for (int j = 0; j < 2; ++j) {
      const int n = N0 + wc * 32 + j * 16 + rA;
#pragma unroll
      for (int r = 0; r < 4; ++r) {
        const int m = M0 + wr * 128 + i * 16 + (kg << 2) + r;
        const float h1 = acc1[i][j][r], h3 = acc3[i][j][r];
        gh[(size_t)m * HIDK + n] = (f16)(h1 * h3 / (1.f + __expf(-h1)));
      }
    }
}

// ============================================================================
// Pipelined output GEMM: out = g@w2^T + 2 t2@B2^T   (256x256, BK=32, K=11008)
// ============================================================================
#define ONT 344  // 11008 / 32
__global__ __launch_bounds__(512, 2) void gemm_out(
    const f16* __restrict__ gh, const f16* __restrict__ w2h,
    const float* __restrict__ t2, const float* __restrict__ B2,
    float* __restrict__ out) {
  __shared__ __align__(16) char lds[131072];  // 4 bufs x (A 16K | B 16K)

  const int bid = (int)blockIdx.x;
  const int wg = (bid & 7) * 64 + (bid >> 3);  // 512 % 8 == 0
  const int tm = wg & 31, tn = wg >> 5;
  const int M0 = tm << 8, N0 = tn << 8;

  const int tid = (int)threadIdx.x;
  const int l = tid & 63, wid = tid >> 6;
  const int wr = wid >> 2, wc = wid & 3;  // 2 x 4 waves -> 128 x 64 per wave
  const int rA = l & 15;

  const int srow = l >> 2;
  const int scol = ((l & 3) ^ ((l >> 3) & 3)) << 4;
  const size_t RS = (size_t)HIDK * 2;  // 22016 B row stride
  const uint8_t* aSrc = (const uint8_t*)gh + (size_t)(M0 + wid * 32 + srow) * RS + scol;
  const uint8_t* bSrc = (const uint8_t*)w2h + (size_t)(N0 + wid * 32 + srow) * RS + scol;

  const int colA = ((l >> 4) ^ ((l >> 1) & 3)) << 4;
  const int aOff = ((wr * 128 + rA) << 6) + colA;
  const int bOff = ((wc * 64 + rA) << 6) + colA;

  const f32x4 zz = {0.f, 0.f, 0.f, 0.f};
  f32x4 acc[8][4];
#pragma unroll
  for (int i = 0; i < 8; ++i)
#pragma unroll
    for (int j = 0; j < 4; ++j) acc[i][j] = zz;

#pragma unroll
  for (int pt = 0; pt < 3; ++pt) {
    const int bb = pt << 15;
    const size_t o = (size_t)pt * 64;
    gld_lds16(aSrc + o, lds + bb + wid * 2048);
    gld_lds16(aSrc + o + 16 * RS, lds + bb + wid * 2048 + 1024);
    gld_lds16(bSrc + o, lds + bb + 16384 + wid * 2048);
    gld_lds16(bSrc + o + 16 * RS, lds + bb + 16384 + wid * 2048 + 1024);
  }
  asm volatile("s_waitcnt vmcnt(8)" ::: "memory");
  __builtin_amdgcn_s_barrier();

  for (int t = 0; t < ONT; ++t) {
    const int bb = (t & 3) << 15;
    f16x8 a[8], b[4];
    // ---- phase A ----
#pragma unroll
    for (int i = 0; i < 4; ++i)
      a[i] = *(const f16x8*)(lds + bb + aOff + i * 1024);
#pragma unroll
    for (int j = 0; j < 4; ++j)
      b[j] = *(const f16x8*)(lds + bb + 16384 + bOff + j * 1024);
    if (t + 3 < ONT) {
      const int nb = ((t + 3) & 3) << 15;
      const size_t o = (size_t)(t + 3) * 64;
      gld_lds16(aSrc + o, lds + nb + wid * 2048);
      gld_lds16(aSrc + o + 16 * RS, lds + nb + wid * 2048 + 1024);
    }
    __builtin_amdgcn_s_barrier();
    asm volatile("s_waitcnt lgkmcnt(0)" ::: "memory");
    __builtin_amdgcn_sched_barrier(0);
    __builtin_amdgcn_s_setprio(1);
#pragma unroll
    for (int i = 0; i < 4; ++i)
#pragma unroll
      for (int j = 0; j < 4; ++j)
        acc[i][j] = __builtin_amdgcn_mfma_f32_16x16x32_f16(a[i], b[j], acc[i][j], 0, 0, 0);
    __builtin_amdgcn_s_setprio(0);
    __builtin_amdgcn_s_barrier();
    // ---- phase B ----
#pragma unroll
    for (int i = 4; i < 8; ++i)
      a[i] = *(const f16x8*)(lds + bb + aOff + i * 1024);
    if (t + 3 < ONT) {
      const int nb = ((t + 3) & 3) << 15;
      const size_t o = (size_t)(t + 3) * 64;
      gld_lds16(bSrc + o, lds + nb + 16384 + wid * 2048);
      gld_lds16(bSrc + o + 16 * RS, lds + nb + 16384 + wid * 2048 + 1024);
    }
    if (t + 3 < ONT)      asm volatile("s_waitcnt vmcnt(8)" ::: "memory");
    else if (t + 3 == ONT) asm volatile("s_waitcnt vmcnt(4)" ::: "memory");
    else if (t + 2 == ONT) asm volatile("s_waitcnt vmcnt(0)" ::: "memory");
    __builtin_amdgcn_s_barrier();
    asm volatile("s_waitcnt lgkmcnt(0)" ::: "memory");
    __builtin_amdgcn_sched_barrier(0);
    __builtin_amdgcn_s_setprio(1);
#pragma unroll
    for (int i = 4; i < 8; ++i)
#pragma unroll
      for (int j = 0; j < 4; ++j)
        acc[i][j] = __builtin_amdgcn_mfma_f32_16x16x32_f16(a[i], b[j], acc[i][j], 0, 0, 0);
    __builtin_amdgcn_s_setprio(0);
    __builtin_amdgcn_s_barrier();
  }

  // ---- LoRA ext step: A=[2 t2|0], B=[B2|0] ----
  const int kg = l >> 4;
  {
    f16x8 bx[4];
#pragma unroll
    for (int j = 0; j < 4; ++j) {
      const int n = N0 + wc * 64 + j * 16 + rA;
#pragma unroll
      for (int e = 0; e < 8; ++e) bx[j][e] = (f16)0.f;
      if (kg < 2) {
        const float4* p = (const float4*)(B2 + (size_t)n * 16 + kg * 8);
        float4 u = p[0], v = p[1];
        bx[j][0]=(f16)u.x; bx[j][1]=(f16)u.y; bx[j][2]=(f16)u.z; bx[j][3]=(f16)u.w;
        bx[j][4]=(f16)v.x; bx[j][5]=(f16)v.y; bx[j][6]=(f16)v.z; bx[j][7]=(f16)v.w;
      }
    }
#pragma unroll
    for (int i = 0; i < 8; ++i) {
      const int m = M0 + wr * 128 + i * 16 + rA;
      f16x8 ax;
#pragma unroll
      for (int e = 0; e < 8; ++e) ax[e] = (f16)0.f;
      if (kg < 2) {
        const float4* p = (const float4*)(t2 + (size_t)m * 16 + kg * 8);
        float4 u = p[0], v = p[1];
        ax[0]=(f16)(2.f*u.x); ax[1]=(f16)(2.f*u.y); ax[2]=(f16)(2.f*u.z); ax[3]=(f16)(2.f*u.w);
        ax[4]=(f16)(2.f*v.x); ax[5]=(f16)(2.f*v.y); ax[6]=(f16)(2.f*v.z); ax[7]=(f16)(2.f*v.w);
      }
#pragma unroll
      for (int j = 0; j < 4; ++j)
        acc[i][j] = __builtin_amdgcn_mfma_f32_16x16x32_f16(ax, bx[j], acc[i][j], 0, 0, 0);
    }
  }

#pragma unroll
  for (int i = 0; i < 8; ++i)
#pragma unroll
    for (int j = 0; j < 4; ++j) {
      const int n = N0 + wc * 64 + j * 16 + rA;
#pragma unroll
      for (int r = 0; r < 4; ++r) {
        const int m = M0 + wr * 128 + i * 16 + (kg << 2) + r;
        out[(size_t)m * DIMK + n] = acc[i][j][r];
      }
    }
}

extern "C" void kernel_launch(void* const* d_in, const int* in_sizes, int n_in,
                              void* d_out, int out_size, void* d_ws,
                              size_t ws_size, hipStream_t stream) {
  (void)in_sizes; (void)n_in; (void)out_size; (void)ws_size;
  const float* x = (const float*)d_in[0];
  const float* w1 = (const float*)d_in[1];
  const float* w3 = (const float*)d_in[2];
  const float* w2 = (const float*)d_in[3];
  const float* A1 = (const float*)d_in[4];
  const float* B1 = (const float*)d_in[5];
  const float* A3 = (const float*)d_in[6];
  const float* B3 = (const float*)d_in[7];
  const float* A2 = (const float*)d_in[8];
  const float* B2 = (const float*)d_in[9];
  float* out = (float*)d_out;
  char* ws = (char*)d_ws;

  f16* xh = (f16*)(ws);                                   //  64 MiB
  f16* w1h = (f16*)(ws + 67108864);                       //  86 MiB
  f16* w3h = (f16*)(ws + 67108864 + 90177536);            //  86 MiB
  f16* w2h = (f16*)(ws + 67108864 + 2 * 90177536);        //  86 MiB
  f16* gh = (f16*)(ws + 67108864 + 3 * 90177536);         // 172 MiB
  float* t1 = (float*)(ws + 67108864 + 3 * 90177536 + 180355072);
  float* t3 = t1 + MTOK * 16;
  float* t2 = t3 + MTOK * 16;

  convertk<<<1024, 256, 0, stream>>>(x, xh, MTOK * DIMK);
  convertk<<<1024, 256, 0, stream>>>(w1, w1h, HIDK * DIMK);
  convertk<<<1024, 256, 0, stream>>>(w3, w3h, HIDK * DIMK);
  convertk<<<1024, 256, 0, stream>>>(w2, w2h, DIMK * HIDK);
  lora_xA<<<MTOK / 4, 256, 0, stream>>>(xh, A1, A3, t1, t3);
  gemm_gate<<<(MTOK / 256) * (HIDK / 128), 512, 0, stream>>>(xh, w1h, w3h, t1,
                                                             t3, B1, B3, gh);
  lora_g<<<MTOK / 4, 256, 0, stream>>>(gh, A2, t2);
  gemm_out<<<(MTOK / 256) * (DIMK / 256), 512, 0, stream>>>(gh, w2h, t2, B2,
                                                            out);
}

// Round 4
// 3149.190 us; speedup vs baseline: 1.1350x; 1.0939x over previous
//
#include <hip/hip_runtime.h>
#include <hip/hip_bf16.h>
#include <cstdint>
#include <cstddef>

typedef _Float16 f16;
typedef _Float16 f16x8 __attribute__((ext_vector_type(8)));
typedef float f32x4 __attribute__((ext_vector_type(4)));

#define DIMK 4096
#define HIDK 11008
#define MTOK 8192

// ---- async global->LDS, 16B per lane, dest = wave-uniform base + lane*16 ----
__device__ __forceinline__ void gld_lds16(const void* g, void* l) {
  __builtin_amdgcn_global_load_lds(
      (const __attribute__((address_space(1))) void*)g,
      (__attribute__((address_space(3))) void*)l, 16, 0, 0);
}

// ---- fp32 -> fp16 convert, 8 elems/thread, grid-stride ----
__global__ __launch_bounds__(256) void convertk(const float* __restrict__ s,
                                                f16* __restrict__ d, int n) {
  for (int i = ((int)blockIdx.x * 256 + (int)threadIdx.x) * 8; i < n;
       i += (int)gridDim.x * 256 * 8) {
    const float4* p = (const float4*)(s + i);
    float4 a = p[0], b = p[1];
    f16x8 o;
    o[0] = (f16)a.x; o[1] = (f16)a.y; o[2] = (f16)a.z; o[3] = (f16)a.w;
    o[4] = (f16)b.x; o[5] = (f16)b.y; o[6] = (f16)b.z; o[7] = (f16)b.w;
    *(f16x8*)(d + i) = o;
  }
}

// ---- t1 = x@A1^T, t3 = x@A3^T  (K=4096, one wave per row) ----
__global__ __launch_bounds__(256) void lora_xA(const f16* __restrict__ xh,
                                               const float* __restrict__ A1,
                                               const float* __restrict__ A3,
                                               float* __restrict__ t1,
                                               float* __restrict__ t3) {
  const int wid = threadIdx.x >> 6, l = threadIdx.x & 63;
  const int m = (int)blockIdx.x * 4 + wid;
  float a1[16], a3[16];
#pragma unroll
  for (int r = 0; r < 16; ++r) { a1[r] = 0.f; a3[r] = 0.f; }
  for (int it = 0; it < 8; ++it) {
    const int k0 = it * 512 + l * 8;
    f16x8 xv = *(const f16x8*)(xh + (size_t)m * DIMK + k0);
    float xf[8];
#pragma unroll
    for (int j = 0; j < 8; ++j) xf[j] = (float)xv[j];
#pragma unroll
    for (int r = 0; r < 16; ++r) {
      const float4* p1 = (const float4*)(A1 + (size_t)r * DIMK + k0);
      float4 u = p1[0], v = p1[1];
      a1[r] += xf[0]*u.x + xf[1]*u.y + xf[2]*u.z + xf[3]*u.w +
               xf[4]*v.x + xf[5]*v.y + xf[6]*v.z + xf[7]*v.w;
      const float4* p3 = (const float4*)(A3 + (size_t)r * DIMK + k0);
      float4 s2 = p3[0], t2v = p3[1];
      a3[r] += xf[0]*s2.x + xf[1]*s2.y + xf[2]*s2.z + xf[3]*s2.w +
               xf[4]*t2v.x + xf[5]*t2v.y + xf[6]*t2v.z + xf[7]*t2v.w;
    }
  }
#pragma unroll
  for (int r = 0; r < 16; ++r) {
    float v1 = a1[r], v3 = a3[r];
#pragma unroll
    for (int off = 32; off > 0; off >>= 1) {
      v1 += __shfl_xor(v1, off);
      v3 += __shfl_xor(v3, off);
    }
    if (l == 0) { t1[m * 16 + r] = v1; t3[m * 16 + r] = v3; }
  }
}

// ---- t2 = g@A2^T (K=11008) ----
__global__ __launch_bounds__(256) void lora_g(const f16* __restrict__ gh,
                                              const float* __restrict__ A2,
                                              float* __restrict__ t2) {
  const int wid = threadIdx.x >> 6, l = threadIdx.x & 63;
  const int m = (int)blockIdx.x * 4 + wid;
  float acc[16];
#pragma unroll
  for (int r = 0; r < 16; ++r) acc[r] = 0.f;
  for (int it = 0; it < 22; ++it) {
    const int k0 = it * 512 + l * 8;
    if (k0 < HIDK) {
      f16x8 gv = *(const f16x8*)(gh + (size_t)m * HIDK + k0);
      float xf[8];
#pragma unroll
      for (int j = 0; j < 8; ++j) xf[j] = (float)gv[j];
#pragma unroll
      for (int r = 0; r < 16; ++r) {
        const float4* p = (const float4*)(A2 + (size_t)r * HIDK + k0);
        float4 u = p[0], v = p[1];
        acc[r] += xf[0]*u.x + xf[1]*u.y + xf[2]*u.z + xf[3]*u.w +
                  xf[4]*v.x + xf[5]*v.y + xf[6]*v.z + xf[7]*v.w;
      }
    }
  }
#pragma unroll
  for (int r = 0; r < 16; ++r) {
    float v = acc[r];
#pragma unroll
    for (int off = 32; off > 0; off >>= 1) v += __shfl_xor(v, off);
    if (l == 0) t2[m * 16 + r] = v;
  }
}

// ============================================================================
// Pipelined dual GEMM: g = silu(x@w1^T + 2 t1@B1^T) * (x@w3^T + 2 t3@B3^T)
// BM=256, BN=128 (x2 outputs), BK=32, 4 LDS buffers, counted vmcnt(8),
// raw s_barrier, setprio. tn-PAIRED ordering: each tm-sweep serves 2 adjacent
// tn panels -> x re-read halves and stays L3-resident. gh stored nontemporal.
// ============================================================================
#define GNT 128  // 4096 / 32
__global__ __launch_bounds__(512, 2) void gemm_gate(
    const f16* __restrict__ xh, const f16* __restrict__ w1h,
    const f16* __restrict__ w3h, const float* __restrict__ t1,
    const float* __restrict__ t3, const float* __restrict__ B1,
    const float* __restrict__ B3, f16* __restrict__ gh) {
  __shared__ __align__(16) char lds[131072];  // 4 bufs x (A 16K | B1 8K | B3 8K)

  const int bid = (int)blockIdx.x;
  const int wg = (bid & 7) * 344 + (bid >> 3);  // XCD swizzle, 2752 % 8 == 0
  const int p = wg >> 6, r0 = wg & 63;          // tn-pair columns (86 tn = 43 pairs)
  const int tm = r0 >> 1, tn = (p << 1) + (r0 & 1);
  const int M0 = tm << 8, N0 = tn << 7;

  const int tid = (int)threadIdx.x;
  const int l = tid & 63, wid = tid >> 6;
  const int wr = wid >> 2, wc = wid & 3;  // 2 x 4 waves -> 128 x 32 per wave
  const int rA = l & 15;

  // staging sources (pre-swizzled global col so linear LDS dest == swizzled)
  const int srow = l >> 2;
  const int scol = ((l & 3) ^ ((l >> 3) & 3)) << 4;
  const uint8_t* aSrc =
      (const uint8_t*)xh + (size_t)(M0 + wid * 32 + srow) * 8192 + scol;
  const uint8_t* b1Src =
      (const uint8_t*)w1h + (size_t)(N0 + wid * 16 + srow) * 8192 + scol;
  const uint8_t* b3Src =
      (const uint8_t*)w3h + (size_t)(N0 + wid * 16 + srow) * 8192 + scol;

  // fragment read offsets (swizzled)
  const int colA = ((l >> 4) ^ ((l >> 1) & 3)) << 4;
  const int aOff = ((wr * 128 + rA) << 6) + colA;  // + i*1024
  const int bOff = ((wc * 32 + rA) << 6) + colA;   // + j*1024

  const f32x4 zz = {0.f, 0.f, 0.f, 0.f};
  f32x4 acc1[8][2], acc3[8][2];
#pragma unroll
  for (int i = 0; i < 8; ++i)
#pragma unroll
    for (int j = 0; j < 2; ++j) { acc1[i][j] = zz; acc3[i][j] = zz; }

  // prologue: stage tiles 0..2
#pragma unroll
  for (int pt = 0; pt < 3; ++pt) {
    const int bb = pt << 15;
    const size_t o = (size_t)pt * 64;
    gld_lds16(aSrc + o, lds + bb + wid * 2048);
    gld_lds16(aSrc + o + 131072, lds + bb + wid * 2048 + 1024);
    gld_lds16(b1Src + o, lds + bb + 16384 + wid * 1024);
    gld_lds16(b3Src + o, lds + bb + 24576 + wid * 1024);
  }
  asm volatile("s_waitcnt vmcnt(8)" ::: "memory");
  __builtin_amdgcn_s_barrier();

  for (int t = 0; t < GNT; ++t) {
    const int bb = (t & 3) << 15;
    f16x8 a[8], b1[2], b3[2];
    // ---- phase A: frags + A-prefetch, MFMA i0-3 ----
#pragma unroll
    for (int i = 0; i < 4; ++i)
      a[i] = *(const f16x8*)(lds + bb + aOff + i * 1024);
#pragma unroll
    for (int j = 0; j < 2; ++j) {
      b1[j] = *(const f16x8*)(lds + bb + 16384 + bOff + j * 1024);
      b3[j] = *(const f16x8*)(lds + bb + 24576 + bOff + j * 1024);
    }
    if (t + 3 < GNT) {
      const int nb = ((t + 3) & 3) << 15;
      const size_t o = (size_t)(t + 3) * 64;
      gld_lds16(aSrc + o, lds + nb + wid * 2048);
      gld_lds16(aSrc + o + 131072, lds + nb + wid * 2048 + 1024);
    }
    __builtin_amdgcn_s_barrier();
    asm volatile("s_waitcnt lgkmcnt(0)" ::: "memory");
    __builtin_amdgcn_sched_barrier(0);
    __builtin_amdgcn_s_setprio(1);
#pragma unroll
    for (int i = 0; i < 4; ++i)
#pragma unroll
      for (int j = 0; j < 2; ++j) {
        acc1[i][j] = __builtin_amdgcn_mfma_f32_16x16x32_f16(a[i], b1[j], acc1[i][j], 0, 0, 0);
        acc3[i][j] = __builtin_amdgcn_mfma_f32_16x16x32_f16(a[i], b3[j], acc3[i][j], 0, 0, 0);
      }
    __builtin_amdgcn_s_setprio(0);
    __builtin_amdgcn_s_barrier();
    // ---- phase B: frags + B-prefetch, counted vmcnt, MFMA i4-7 ----
#pragma unroll
    for (int i = 4; i < 8; ++i)
      a[i] = *(const f16x8*)(lds + bb + aOff + i * 1024);
    if (t + 3 < GNT) {
      const int nb = ((t + 3) & 3) << 15;
      const size_t o = (size_t)(t + 3) * 64;
      gld_lds16(b1Src + o, lds + nb + 16384 + wid * 1024);
      gld_lds16(b3Src + o, lds + nb + 24576 + wid * 1024);
    }
    if (t + 3 < GNT)      asm volatile("s_waitcnt vmcnt(8)" ::: "memory");
    else if (t + 3 == GNT) asm volatile("s_waitcnt vmcnt(4)" ::: "memory");
    else if (t + 2 == GNT) asm volatile("s_waitcnt vmcnt(0)" ::: "memory");
    __builtin_amdgcn_s_barrier();
    asm volatile("s_waitcnt lgkmcnt(0)" ::: "memory");
    __builtin_amdgcn_sched_barrier(0);
    __builtin_amdgcn_s_setprio(1);
#pragma unroll
    for (int i = 4; i < 8; ++i)
#pragma unroll
      for (int j = 0; j < 2; ++j) {
        acc1[i][j] = __builtin_amdgcn_mfma_f32_16x16x32_f16(a[i], b1[j], acc1[i][j], 0, 0, 0);
        acc3[i][j] = __builtin_amdgcn_mfma_f32_16x16x32_f16(a[i], b3[j], acc3[i][j], 0, 0, 0);
      }
    __builtin_amdgcn_s_setprio(0);
    __builtin_amdgcn_s_barrier();
  }

  // ---- LoRA ext K=32 step, register-direct: A=[2t1|2t3], B1e=[B1|0], B3e=[0|B3]
  const int kg = l >> 4;
  {
    f16x8 bx1[2], bx3[2];
#pragma unroll
    for (int j = 0; j < 2; ++j) {
      const int n = N0 + wc * 32 + j * 16 + rA;
#pragma unroll
      for (int e = 0; e < 8; ++e) { bx1[j][e] = (f16)0.f; bx3[j][e] = (f16)0.f; }
      if (kg < 2) {
        const float4* p2 = (const float4*)(B1 + (size_t)n * 16 + kg * 8);
        float4 u = p2[0], v = p2[1];
        bx1[j][0]=(f16)u.x; bx1[j][1]=(f16)u.y; bx1[j][2]=(f16)u.z; bx1[j][3]=(f16)u.w;
        bx1[j][4]=(f16)v.x; bx1[j][5]=(f16)v.y; bx1[j][6]=(f16)v.z; bx1[j][7]=(f16)v.w;
      } else {
        const float4* p2 = (const float4*)(B3 + (size_t)n * 16 + (kg - 2) * 8);
        float4 u = p2[0], v = p2[1];
        bx3[j][0]=(f16)u.x; bx3[j][1]=(f16)u.y; bx3[j][2]=(f16)u.z; bx3[j][3]=(f16)u.w;
        bx3[j][4]=(f16)v.x; bx3[j][5]=(f16)v.y; bx3[j][6]=(f16)v.z; bx3[j][7]=(f16)v.w;
      }
    }
#pragma unroll
    for (int i = 0; i < 8; ++i) {
      const int m = M0 + wr * 128 + i * 16 + rA;
      const float* src = (kg < 2) ? (t1 + (size_t)m * 16 + kg * 8)
                                  : (t3 + (size_t)m * 16 + (kg - 2) * 8);
      const float4* p2 = (const float4*)src;
      float4 u = p2[0], v = p2[1];
      f16x8 ax;
      ax[0]=(f16)(2.f*u.x); ax[1]=(f16)(2.f*u.y); ax[2]=(f16)(2.f*u.z); ax[3]=(f16)(2.f*u.w);
      ax[4]=(f16)(2.f*v.x); ax[5]=(f16)(2.f*v.y); ax[6]=(f16)(2.f*v.z); ax[7]=(f16)(2.f*v.w);
#pragma unroll
      for (int j = 0; j < 2; ++j) {
        acc1[i][j] = __builtin_amdgcn_mfma_f32_16x16x32_f16(ax, bx1[j], acc1[i][j], 0, 0, 0);
        acc3[i][j] = __builtin_amdgcn_mfma_f32_16x16x32_f16(ax, bx3[j], acc3[i][j], 0, 0, 0);
      }
    }
  }

  // ---- epilogue: g = silu(h1) * h3, nontemporal store ----
#pragma unroll
  for (int i = 0; i < 8; ++i)
#pragma unroll
    for (int j = 0; j < 2; ++j) {
      const int n = N0 + wc * 32 + j * 16 + rA;
#pragma unroll
      for (int rr = 0; rr < 4; ++rr) {
        const int m = M0 + wr * 128 + i * 16 + (kg << 2) + rr;
        const float h1 = acc1[i][j][rr], h3 = acc3[i][j][rr];
        __builtin_nontemporal_store((f16)(h1 * h3 / (1.f + __expf(-h1))),
                                    &gh[(size_t)m * HIDK + n]);
      }
    }
}

// ============================================================================
// Pipelined output GEMM: out = g@w2^T + 2 t2@B2^T   (256x256, BK=32, K=11008)
// tn-paired ordering; out stored nontemporal.
// ============================================================================
#define ONT 344  // 11008 / 32
__global__ __launch_bounds__(512, 2) void gemm_out(
    const f16* __restrict__ gh, const f16* __restrict__ w2h,
    const float* __restrict__ t2, const float* __restrict__ B2,
    float* __restrict__ out) {
  __shared__ __align__(16) char lds[131072];  // 4 bufs x (A 16K | B 16K)

  const int bid = (int)blockIdx.x;
  const int wg = (bid & 7) * 64 + (bid >> 3);  // 512 % 8 == 0
  const int p = wg >> 6, r0 = wg & 63;         // tn-pairs (16 tn = 8 pairs)
  const int tm = r0 >> 1, tn = (p << 1) + (r0 & 1);
  const int M0 = tm << 8, N0 = tn << 8;

  const int tid = (int)threadIdx.x;
  const int l = tid & 63, wid = tid >> 6;
  const int wr = wid >> 2, wc = wid & 3;  // 2 x 4 waves -> 128 x 64 per wave
  const int rA = l & 15;

  const int srow = l >> 2;
  const int scol = ((l & 3) ^ ((l >> 3) & 3)) << 4;
  const size_t RS = (size_t)HIDK * 2;  // 22016 B row stride
  const uint8_t* aSrc = (const uint8_t*)gh + (size_t)(M0 + wid * 32 + srow) * RS + scol;
  const uint8_t* bSrc = (const uint8_t*)w2h + (size_t)(N0 + wid * 32 + srow) * RS + scol;

  const int colA = ((l >> 4) ^ ((l >> 1) & 3)) << 4;
  const int aOff = ((wr * 128 + rA) << 6) + colA;
  const int bOff = ((wc * 64 + rA) << 6) + colA;

  const f32x4 zz = {0.f, 0.f, 0.f, 0.f};
  f32x4 acc[8][4];
#pragma unroll
  for (int i = 0; i < 8; ++i)
#pragma unroll
    for (int j = 0; j < 4; ++j) acc[i][j] = zz;

#pragma unroll
  for (int pt = 0; pt < 3; ++pt) {
    const int bb = pt << 15;
    const size_t o = (size_t)pt * 64;
    gld_lds16(aSrc + o, lds + bb + wid * 2048);
    gld_lds16(aSrc + o + 16 * RS, lds + bb + wid * 2048 + 1024);
    gld_lds16(bSrc + o, lds + bb + 16384 + wid * 2048);
    gld_lds16(bSrc + o + 16 * RS, lds + bb + 16384 + wid * 2048 + 1024);
  }
  asm volatile("s_waitcnt vmcnt(8)" ::: "memory");
  __builtin_amdgcn_s_barrier();

  for (int t = 0; t < ONT; ++t) {
    const int bb = (t & 3) << 15;
    f16x8 a[8], b[4];
    // ---- phase A ----
#pragma unroll
    for (int i = 0; i < 4; ++i)
      a[i] = *(const f16x8*)(lds + bb + aOff + i * 1024);
#pragma unroll
    for (int j = 0; j < 4; ++j)
      b[j] = *(const f16x8*)(lds + bb + 16384 + bOff + j * 1024);
    if (t + 3 < ONT) {
      const int nb = ((t + 3) & 3) << 15;
      const size_t o = (size_t)(t + 3) * 64;
      gld_lds16(aSrc + o, lds + nb + wid * 2048);
      gld_lds16(aSrc + o + 16 * RS, lds + nb + wid * 2048 + 1024);
    }
    __builtin_amdgcn_s_barrier();
    asm volatile("s_waitcnt lgkmcnt(0)" ::: "memory");
    __builtin_amdgcn_sched_barrier(0);
    __builtin_amdgcn_s_setprio(1);
#pragma unroll
    for (int i = 0; i < 4; ++i)
#pragma unroll
      for (int j = 0; j < 4; ++j)
        acc[i][j] = __builtin_amdgcn_mfma_f32_16x16x32_f16(a[i], b[j], acc[i][j], 0, 0, 0);
    __builtin_amdgcn_s_setprio(0);
    __builtin_amdgcn_s_barrier();
    // ---- phase B ----
#pragma unroll
    for (int i = 4; i < 8; ++i)
      a[i] = *(const f16x8*)(lds + bb + aOff + i * 1024);
    if (t + 3 < ONT) {
      const int nb = ((t + 3) & 3) << 15;
      const size_t o = (size_t)(t + 3) * 64;
      gld_lds16(bSrc + o, lds + nb + 16384 + wid * 2048);
      gld_lds16(bSrc + o + 16 * RS, lds + nb + 16384 + wid * 2048 + 1024);
    }
    if (t + 3 < ONT)      asm volatile("s_waitcnt vmcnt(8)" ::: "memory");
    else if (t + 3 == ONT) asm volatile("s_waitcnt vmcnt(4)" ::: "memory");
    else if (t + 2 == ONT) asm volatile("s_waitcnt vmcnt(0)" ::: "memory");
    __builtin_amdgcn_s_barrier();
    asm volatile("s_waitcnt lgkmcnt(0)" ::: "memory");
    __builtin_amdgcn_sched_barrier(0);
    __builtin_amdgcn_s_setprio(1);
#pragma unroll
    for (int i = 4; i < 8; ++i)
#pragma unroll
      for (int j = 0; j < 4; ++j)
        acc[i][j] = __builtin_amdgcn_mfma_f32_16x16x32_f16(a[i], b[j], acc[i][j], 0, 0, 0);
    __builtin_amdgcn_s_setprio(0);
    __builtin_amdgcn_s_barrier();
  }

  // ---- LoRA ext step: A=[2 t2|0], B=[B2|0] ----
  const int kg = l >> 4;
  {
    f16x8 bx[4];
#pragma unroll
    for (int j = 0; j < 4; ++j) {
      const int n = N0 + wc * 64 + j * 16 + rA;
#pragma unroll
      for (int e = 0; e < 8; ++e) bx[j][e] = (f16)0.f;
      if (kg < 2) {
        const float4* p2 = (const float4*)(B2 + (size_t)n * 16 + kg * 8);
        float4 u = p2[0], v = p2[1];
        bx[j][0]=(f16)u.x; bx[j][1]=(f16)u.y; bx[j][2]=(f16)u.z; bx[j][3]=(f16)u.w;
        bx[j][4]=(f16)v.x; bx[j][5]=(f16)v.y; bx[j][6]=(f16)v.z; bx[j][7]=(f16)v.w;
      }
    }
#pragma unroll
    for (int i = 0; i < 8; ++i) {
      const int m = M0 + wr * 128 + i * 16 + rA;
      f16x8 ax;
#pragma unroll
      for (int e = 0; e < 8; ++e) ax[e] = (f16)0.f;
      if (kg < 2) {
        const float4* p2 = (const float4*)(t2 + (size_t)m * 16 + kg * 8);
        float4 u = p2[0], v = p2[1];
        ax[0]=(f16)(2.f*u.x); ax[1]=(f16)(2.f*u.y); ax[2]=(f16)(2.f*u.z); ax[3]=(f16)(2.f*u.w);
        ax[4]=(f16)(2.f*v.x); ax[5]=(f16)(2.f*v.y); ax[6]=(f16)(2.f*v.z); ax[7]=(f16)(2.f*v.w);
      }
#pragma unroll
      for (int j = 0; j < 4; ++j)
        acc[i][j] = __builtin_amdgcn_mfma_f32_16x16x32_f16(ax, bx[j], acc[i][j], 0, 0, 0);
    }
  }

#pragma unroll
  for (int i = 0; i < 8; ++i)
#pragma unroll
    for (int j = 0; j < 4; ++j) {
      const int n = N0 + wc * 64 + j * 16 + rA;
#pragma unroll
      for (int rr = 0; rr < 4; ++rr) {
        const int m = M0 + wr * 128 + i * 16 + (kg << 2) + rr;
        __builtin_nontemporal_store(acc[i][j][rr], &out[(size_t)m * DIMK + n]);
      }
    }
}

extern "C" void kernel_launch(void* const* d_in, const int* in_sizes, int n_in,
                              void* d_out, int out_size, void* d_ws,
                              size_t ws_size, hipStream_t stream) {
  (void)in_sizes; (void)n_in; (void)out_size; (void)ws_size;
  const float* x = (const float*)d_in[0];
  const float* w1 = (const float*)d_in[1];
  const float* w3 = (const float*)d_in[2];
  const float* w2 = (const float*)d_in[3];
  const float* A1 = (const float*)d_in[4];
  const float* B1 = (const float*)d_in[5];
  const float* A3 = (const float*)d_in[6];
  const float* B3 = (const float*)d_in[7];
  const float* A2 = (const float*)d_in[8];
  const float* B2 = (const float*)d_in[9];
  float* out = (float*)d_out;
  char* ws = (char*)d_ws;

  f16* xh = (f16*)(ws);                                   //  64 MiB
  f16* w1h = (f16*)(ws + 67108864);                       //  86 MiB
  f16* w3h = (f16*)(ws + 67108864 + 90177536);            //  86 MiB
  f16* w2h = (f16*)(ws + 67108864 + 2 * 90177536);        //  86 MiB
  f16* gh = (f16*)(ws + 67108864 + 3 * 90177536);         // 172 MiB
  float* t1 = (float*)(ws + 67108864 + 3 * 90177536 + 180355072);
  float* t3 = t1 + MTOK * 16;
  float* t2 = t3 + MTOK * 16;

  convertk<<<1024, 256, 0, stream>>>(x, xh, MTOK * DIMK);
  convertk<<<1024, 256, 0, stream>>>(w1, w1h, HIDK * DIMK);
  convertk<<<1024, 256, 0, stream>>>(w3, w3h, HIDK * DIMK);
  convertk<<<1024, 256, 0, stream>>>(w2, w2h, DIMK * HIDK);
  lora_xA<<<MTOK / 4, 256, 0, stream>>>(xh, A1, A3, t1, t3);
  gemm_gate<<<(MTOK / 256) * (HIDK / 128), 512, 0, stream>>>(xh, w1h, w3h, t1,
                                                             t3, B1, B3, gh);
  lora_g<<<MTOK / 4, 256, 0, stream>>>(gh, A2, t2);
  gemm_out<<<(MTOK / 256) * (DIMK / 256), 512, 0, stream>>>(gh, w2h, t2, B2,
                                                            out);
}